// Round 7
// baseline (12552.200 us; speedup 1.0000x reference)
//
#include <hip/hip_runtime.h>
#include <cstdint>

// ---- problem constants ----
#define NT  4
#define NB  32
#define NC  512
#define NCH 2048
#define NN  196
#define NM  (NB * NN)   // 6272 columns = 98*64
#define NH  8

struct GP {
    const float *q_bn_s, *q_bn_b, *k_bn_s, *k_bn_b;
    const float *proj_b, *proj_bn_s, *proj_bn_b;
    const float *mlp1_b, *mlp1_bn_s, *mlp1_bn_b;
    const float *mlp2_b, *mlp2_bn_s, *mlp2_bn_b;
    const float *wqkP, *wprojP, *wmlp1P, *wmlp2P;  // packed [ot][c][32]
    const float *xT;                                // [T][C][M] permuted input
    float *xy;                                      // [C][M] x + y_spike (per t)
    float *v_q, *v_k, *v_y, *v_h1, *v_h2, *v_attn;  // LIF states, [C][M]
    unsigned char *q_sp, *k_sp, *x_one, *h1_sp, *attn_sp; // binary spikes
    float *out;
    int t;
};

// Exact-f32 LIF step (bitwise-validated vs reference in R2-R6).
__device__ __forceinline__ float lif_step(float z, float v_old, float vth, int& sp) {
    float d = __fsub_rn(z, v_old);
    float h = __fmul_rn(d, 0.5f);
    float v = __fadd_rn(v_old, h);
    sp = (v >= vth) ? 1 : 0;
    return sp ? 0.0f : v;
}

// ---------------- pre-kernels ----------------

// packed transpose: dst[((slab_base + o0/32)*K + c)*32 + j] = src[(o0+j)*K + c]
__global__ __launch_bounds__(256) void trwp_k(const float* __restrict__ src,
                                              float* __restrict__ dst,
                                              int K, int slab_base) {
    __shared__ float tle[32][33];
    const int c0 = blockIdx.x * 32, o0 = blockIdx.y * 32;
    const int tx = threadIdx.x & 31, ty = threadIdx.x >> 5;
#pragma unroll
    for (int r = 0; r < 4; ++r)
        tle[ty + r * 8][tx] = src[(size_t)(o0 + ty + r * 8) * K + c0 + tx];
    __syncthreads();
    const size_t s = slab_base + (o0 >> 5);
#pragma unroll
    for (int r = 0; r < 4; ++r)
        dst[(s * K + c0 + ty + r * 8) * 32 + tx] = tle[tx][ty + r * 8];
}

// xT[t][c][b][n] = x[t][b][c][n]
__global__ __launch_bounds__(64) void permx_k(const float* __restrict__ x,
                                              float* __restrict__ xT) {
    const int id = blockIdx.x;         // t*16384 + c*32 + b
    const int b = id & 31;
    const int c = (id >> 5) & 511;
    const int t = id >> 14;
    const float* s = x + ((size_t)(t * NB + b) * NC + c) * NN;
    float* d = xT + ((size_t)(t * NC + c) * NB + b) * NN;
    for (int n = threadIdx.x; n < NN; n += 64) d[n] = s[n];
}

// attn LIF: per (h,m): integer sum of 64 q-spike bytes; LIF vth=0.5
__global__ __launch_bounds__(256) void attn_k(GP gp) {
    const int m = blockIdx.x * 256 + threadIdx.x;
    const int h = blockIdx.y;
    if (m >= NM) return;
    const unsigned char* q = gp.q_sp + (size_t)h * 64 * NM + m;
    int s = 0;
#pragma unroll 8
    for (int d = 0; d < 64; ++d) s += q[(size_t)d * NM];
    float v = gp.t ? gp.v_attn[(size_t)h * NM + m] : 0.0f;
    int sp;
    v = lif_step((float)s, v, 0.5f, sp);
    gp.v_attn[(size_t)h * NM + m] = v;
    gp.attn_sp[(size_t)h * NM + m] = (unsigned char)sp;
}

// x_one = k_sp AND attn_sp (binary product, exact)
__global__ __launch_bounds__(256) void xone_k(GP gp) {
    const int c = blockIdx.y;
    const int m4 = (blockIdx.x * 256 + threadIdx.x) * 4;
    if (m4 >= NM) return;
    const unsigned int kv = *(const unsigned int*)(gp.k_sp + (size_t)c * NM + m4);
    const unsigned int av = *(const unsigned int*)(gp.attn_sp + (size_t)(c >> 6) * NM + m4);
    *(unsigned int*)(gp.x_one + (size_t)c * NM + m4) = kv & av;
}

// ---------------- fused GEMM + BN + LIF: SGPR-broadcast, LDS-free ----------------
// Each WAVE independently computes o-tile (32 rows) x m-tile (64 cols = lanes).
// Weights are wave-uniform -> scalar loads (s_load) from packed [ot][c][32];
// X is per-lane (lane = column m), 1 coalesced dword/byte load per c.
// No LDS, no barriers. Accumulation strictly sequential in c per output.
// MODE 0: q&k (O=1024,K=512), X=xT[t]   unfused mul+add
// MODE 1: proj (O=512,K=512), X=x_one   fma (binary operand -> exact)
// MODE 2: mlp1 (O=2048,K=512), X=xy     unfused mul+add
// MODE 3: mlp2 (O=512,K=2048), X=h1_sp  fma; writes out
template <int MODE>
__global__ __launch_bounds__(256) void gemm_lif(GP gp) {
    constexpr bool FUSED = (MODE == 1 || MODE == 3);
    constexpr int K = (MODE == 3) ? 2048 : 512;

    const int lane = threadIdx.x & 63;
    const int wid = threadIdx.x >> 6;
    const int ot = blockIdx.y * 4 + wid;      // o-tile (32 channels)
    const int m = blockIdx.x * 64 + lane;     // column

    const float* wP = (MODE == 0) ? gp.wqkP : (MODE == 1) ? gp.wprojP
                    : (MODE == 2) ? gp.wmlp1P : gp.wmlp2P;
    const float* wp = wP + (size_t)ot * K * 32;     // packed: [c][32] contiguous

    const float* xf = (MODE == 0) ? gp.xT + (size_t)gp.t * NC * NM
                    : (MODE == 2) ? gp.xy : nullptr;
    const unsigned char* xu = (MODE == 1) ? gp.x_one : gp.h1_sp;

    float acc[32];
#pragma unroll
    for (int j = 0; j < 32; ++j) acc[j] = 0.0f;

    // ---- pipelined inner loop: W ping-pong (scalar), X 4-deep rotation ----
    float wcur[32];
#pragma unroll
    for (int j = 0; j < 32; ++j) wcur[j] = wp[j];

    float xrf[4];
    unsigned char xrb[4];
#pragma unroll
    for (int u = 0; u < 4; ++u) {
        if constexpr (FUSED) xrb[u] = xu[(size_t)u * NM + m];
        else                 xrf[u] = xf[(size_t)u * NM + m];
    }

#define LOADW(dst, cc)                                                     \
    {                                                                      \
        const int c_ = ((cc) < K - 1) ? (cc) : (K - 1);                    \
        const float* p_ = wp + (size_t)c_ * 32;                            \
        _Pragma("unroll") for (int j = 0; j < 32; ++j) dst[j] = p_[j];     \
    }
#define LOADX(dst, u, cc)                                                  \
    {                                                                      \
        const int c_ = ((cc) < K - 1) ? (cc) : (K - 1);                    \
        if constexpr (FUSED) dst[u] = xu[(size_t)c_ * NM + m];             \
        else                 dst[u] = xf[(size_t)c_ * NM + m];             \
    }
#define MACS(w, xval)                                                      \
    {                                                                      \
        const float xv_ = (xval);                                          \
        _Pragma("unroll") for (int j = 0; j < 32; ++j) {                   \
            if constexpr (FUSED) acc[j] = __fmaf_rn(w[j], xv_, acc[j]);    \
            else acc[j] = __fadd_rn(acc[j], __fmul_rn(w[j], xv_));         \
        }                                                                  \
    }

#pragma unroll 1
    for (int c = 0; c < K; c += 4) {
        float w1[32], w2[32], w3[32], w4[32];
        float xnf[4];
        unsigned char xnb[4];

        LOADW(w1, c + 1);
        if constexpr (FUSED) { LOADX(xnb, 0, c + 4) } else { LOADX(xnf, 0, c + 4) }
        MACS(wcur, FUSED ? (float)xrb[0] : xrf[0]);

        LOADW(w2, c + 2);
        if constexpr (FUSED) { LOADX(xnb, 1, c + 5) } else { LOADX(xnf, 1, c + 5) }
        MACS(w1, FUSED ? (float)xrb[1] : xrf[1]);

        LOADW(w3, c + 3);
        if constexpr (FUSED) { LOADX(xnb, 2, c + 6) } else { LOADX(xnf, 2, c + 6) }
        MACS(w2, FUSED ? (float)xrb[2] : xrf[2]);

        LOADW(w4, c + 4);
        if constexpr (FUSED) { LOADX(xnb, 3, c + 7) } else { LOADX(xnf, 3, c + 7) }
        MACS(w3, FUSED ? (float)xrb[3] : xrf[3]);

#pragma unroll
        for (int j = 0; j < 32; ++j) wcur[j] = w4[j];
#pragma unroll
        for (int u = 0; u < 4; ++u) {
            if constexpr (FUSED) xrb[u] = xnb[u];
            else                 xrf[u] = xnf[u];
        }
    }
#undef LOADW
#undef LOADX
#undef MACS

    // ---- epilogue: BN + LIF, exact reference op order ----
    if constexpr (MODE == 0) {
        const bool isq = (ot < 16);
        const float* bs = isq ? gp.q_bn_s : gp.k_bn_s;
        const float* bbv = isq ? gp.q_bn_b : gp.k_bn_b;
        float* vb = isq ? gp.v_q : gp.v_k;
        unsigned char* sb = isq ? gp.q_sp : gp.k_sp;
        const int ob = (ot & 15) * 32;
#pragma unroll
        for (int j = 0; j < 32; ++j) {
            const int oo = ob + j;
            const float z = __fadd_rn(__fmul_rn(acc[j], bs[oo]), bbv[oo]);
            float v = gp.t ? vb[(size_t)oo * NM + m] : 0.0f;
            int sp;
            v = lif_step(z, v, 1.0f, sp);
            vb[(size_t)oo * NM + m] = v;
            sb[(size_t)oo * NM + m] = (unsigned char)sp;
        }
    } else if constexpr (MODE == 2) {
        const int ob = ot * 32;
#pragma unroll
        for (int j = 0; j < 32; ++j) {
            const int o = ob + j;
            const float z = __fadd_rn(__fmul_rn(__fadd_rn(acc[j], gp.mlp1_b[o]),
                                                gp.mlp1_bn_s[o]), gp.mlp1_bn_b[o]);
            float v = gp.t ? gp.v_h1[(size_t)o * NM + m] : 0.0f;
            int sp;
            v = lif_step(z, v, 1.0f, sp);
            gp.v_h1[(size_t)o * NM + m] = v;
            gp.h1_sp[(size_t)o * NM + m] = (unsigned char)sp;
        }
    } else if constexpr (MODE == 1) {
        const int ob = ot * 32;
#pragma unroll
        for (int j = 0; j < 32; ++j) {
            const int o = ob + j;
            const float z = __fadd_rn(__fmul_rn(__fadd_rn(acc[j], gp.proj_b[o]),
                                                gp.proj_bn_s[o]), gp.proj_bn_b[o]);
            float v = gp.t ? gp.v_y[(size_t)o * NM + m] : 0.0f;
            int sp;
            v = lif_step(z, v, 1.0f, sp);
            gp.v_y[(size_t)o * NM + m] = v;
            const float xo = gp.xT[((size_t)gp.t * NC + o) * NM + m];
            gp.xy[(size_t)o * NM + m] = __fadd_rn(xo, (float)sp);  // residual x + y
        }
    } else {  // MODE 3
        const int ob = ot * 32;
        const int b = m / NN;
        const int n = m - b * NN;
#pragma unroll
        for (int j = 0; j < 32; ++j) {
            const int o = ob + j;
            const float z = __fadd_rn(__fmul_rn(__fadd_rn(acc[j], gp.mlp2_b[o]),
                                                gp.mlp2_bn_s[o]), gp.mlp2_bn_b[o]);
            float v = gp.t ? gp.v_h2[(size_t)o * NM + m] : 0.0f;
            int sp;
            v = lif_step(z, v, 1.0f, sp);
            gp.v_h2[(size_t)o * NM + m] = v;
            const float xyv = gp.xy[(size_t)o * NM + m];
            gp.out[(((size_t)gp.t * NB + b) * NC + o) * NN + n] = __fadd_rn(xyv, (float)sp);
        }
    }
}

extern "C" void kernel_launch(void* const* d_in, const int* in_sizes, int n_in,
                              void* d_out, int out_size, void* d_ws, size_t ws_size,
                              hipStream_t stream) {
    const float* x       = (const float*)d_in[0];
    const float* q_w     = (const float*)d_in[1];
    const float* k_w     = (const float*)d_in[4];
    const float* proj_w  = (const float*)d_in[7];
    const float* mlp1_w  = (const float*)d_in[11];
    const float* mlp2_w  = (const float*)d_in[15];

    GP gp;
    gp.q_bn_s = (const float*)d_in[2];  gp.q_bn_b = (const float*)d_in[3];
    gp.k_bn_s = (const float*)d_in[5];  gp.k_bn_b = (const float*)d_in[6];
    gp.proj_b = (const float*)d_in[8];  gp.proj_bn_s = (const float*)d_in[9];  gp.proj_bn_b = (const float*)d_in[10];
    gp.mlp1_b = (const float*)d_in[12]; gp.mlp1_bn_s = (const float*)d_in[13]; gp.mlp1_bn_b = (const float*)d_in[14];
    gp.mlp2_b = (const float*)d_in[16]; gp.mlp2_bn_s = (const float*)d_in[17]; gp.mlp2_bn_b = (const float*)d_in[18];
    gp.out = (float*)d_out;

    char* ws = (char*)d_ws;
    size_t off = 0;
    auto alloc = [&](size_t bytes) -> void* {
        void* r = ws + off;
        off += (bytes + 255) & ~(size_t)255;
        return r;
    };
    float* wqkP   = (float*)alloc((size_t)512 * 1024 * 4);
    float* wprojP = (float*)alloc((size_t)512 * 512 * 4);
    float* wmlp1P = (float*)alloc((size_t)512 * 2048 * 4);
    float* wmlp2P = (float*)alloc((size_t)2048 * 512 * 4);
    float* xT     = (float*)alloc((size_t)NT * NC * NM * 4);
    gp.xy     = (float*)alloc((size_t)NC * NM * 4);
    gp.v_q    = (float*)alloc((size_t)NC * NM * 4);
    gp.v_k    = (float*)alloc((size_t)NC * NM * 4);
    gp.v_y    = (float*)alloc((size_t)NC * NM * 4);
    gp.v_h2   = (float*)alloc((size_t)NC * NM * 4);
    gp.v_h1   = (float*)alloc((size_t)NCH * NM * 4);
    gp.v_attn = (float*)alloc((size_t)NH * NM * 4);
    gp.q_sp   = (unsigned char*)alloc((size_t)NC * NM);
    gp.k_sp   = (unsigned char*)alloc((size_t)NC * NM);
    gp.x_one  = (unsigned char*)alloc((size_t)NC * NM);
    gp.h1_sp  = (unsigned char*)alloc((size_t)NCH * NM);
    gp.attn_sp= (unsigned char*)alloc((size_t)NH * NM);
    gp.wqkP = wqkP; gp.wprojP = wprojP; gp.wmlp1P = wmlp1P; gp.wmlp2P = wmlp2P;
    gp.xT = xT;

    // one-time (per call) layout transforms: packed [ot][c][32] weight slabs
    trwp_k<<<dim3(16, 16), 256, 0, stream>>>(q_w,    wqkP,   512,  0);
    trwp_k<<<dim3(16, 16), 256, 0, stream>>>(k_w,    wqkP,   512,  16);
    trwp_k<<<dim3(16, 16), 256, 0, stream>>>(proj_w, wprojP, 512,  0);
    trwp_k<<<dim3(16, 64), 256, 0, stream>>>(mlp1_w, wmlp1P, 512,  0);
    trwp_k<<<dim3(64, 16), 256, 0, stream>>>(mlp2_w, wmlp2P, 2048, 0);
    permx_k<<<NT * NC * NB, 64, 0, stream>>>(x, xT);

    for (int t = 0; t < NT; ++t) {
        gp.t = t;
        gemm_lif<0><<<dim3(98, 8), 256, 0, stream>>>(gp);   // q,k
        attn_k<<<dim3(25, NH), 256, 0, stream>>>(gp);       // attn LIF
        xone_k<<<dim3(7, NC), 256, 0, stream>>>(gp);        // k_sp & attn_sp
        gemm_lif<1><<<dim3(98, 4), 256, 0, stream>>>(gp);   // proj -> v_y, xy
        gemm_lif<2><<<dim3(98, 16), 256, 0, stream>>>(gp);  // mlp1 -> h1_sp
        gemm_lif<3><<<dim3(98, 4), 256, 0, stream>>>(gp);   // mlp2 -> out
    }
}

// Round 8
// 2586.300 us; speedup vs baseline: 4.8533x; 4.8533x over previous
//
#include <hip/hip_runtime.h>
#include <cstdint>

// ---- problem constants ----
#define NT  4
#define NB  32
#define NC  512
#define NCH 2048
#define NN  196
#define NM  (NB * NN)   // 6272 columns = 98*64
#define NH  8

struct GP {
    const float *q_bn_s, *q_bn_b, *k_bn_s, *k_bn_b;
    const float *proj_b, *proj_bn_s, *proj_bn_b;
    const float *mlp1_b, *mlp1_bn_s, *mlp1_bn_b;
    const float *mlp2_b, *mlp2_bn_s, *mlp2_bn_b;
    const float *wqkT, *wprojT, *wmlp1T, *wmlp2T;  // [K][O] transposed weights
    const float *xT;                                // [T][C][M] permuted input
    float *xy;                                      // [C][M] x + y_spike (per t)
    float *v_q, *v_k, *v_y, *v_h1, *v_h2, *v_attn;  // LIF states, [C][M]
    unsigned char *q_sp, *k_sp, *x_one, *h1_sp, *attn_sp; // binary spikes
    float *out;
    int t;
};

// Exact-f32 LIF step (bitwise-validated vs reference in R2-R7).
__device__ __forceinline__ float lif_step(float z, float v_old, float vth, int& sp) {
    float d = __fsub_rn(z, v_old);
    float h = __fmul_rn(d, 0.5f);
    float v = __fadd_rn(v_old, h);
    sp = (v >= vth) ? 1 : 0;
    return sp ? 0.0f : v;
}

typedef const void __attribute__((address_space(1))) gas_t;
typedef void __attribute__((address_space(3))) las_t;
__device__ __forceinline__ void gl_lds16(const float* g, float* l) {
    __builtin_amdgcn_global_load_lds((gas_t*)g, (las_t*)l, 16, 0, 0);
}
__device__ __forceinline__ void vm0() {
    asm volatile("s_waitcnt vmcnt(0)" ::: "memory");
}
__device__ __forceinline__ void lgkm0() {
    asm volatile("s_waitcnt lgkmcnt(0)" ::: "memory");
}

// ---------------- pre-kernels ----------------

// dst[c*ldD + offD + o] = src[o*K + c]   (32x32 LDS tiles)
__global__ __launch_bounds__(256) void trw_k(const float* __restrict__ src,
                                             float* __restrict__ dst,
                                             int K, int ldD, int offD) {
    __shared__ float tle[32][33];
    const int c0 = blockIdx.x * 32, o0 = blockIdx.y * 32;
    const int tx = threadIdx.x & 31, ty = threadIdx.x >> 5;
#pragma unroll
    for (int r = 0; r < 4; ++r)
        tle[ty + r * 8][tx] = src[(size_t)(o0 + ty + r * 8) * K + c0 + tx];
    __syncthreads();
#pragma unroll
    for (int r = 0; r < 4; ++r)
        dst[(size_t)(c0 + ty + r * 8) * ldD + offD + o0 + tx] = tle[tx][ty + r * 8];
}

// xT[t][c][b][n] = x[t][b][c][n]
__global__ __launch_bounds__(64) void permx_k(const float* __restrict__ x,
                                              float* __restrict__ xT) {
    const int id = blockIdx.x;         // t*16384 + c*32 + b
    const int b = id & 31;
    const int c = (id >> 5) & 511;
    const int t = id >> 14;
    const float* s = x + ((size_t)(t * NB + b) * NC + c) * NN;
    float* d = xT + ((size_t)(t * NC + c) * NB + b) * NN;
    for (int n = threadIdx.x; n < NN; n += 64) d[n] = s[n];
}

// attn LIF: per (h,m): integer sum of 64 q-spike bytes; LIF vth=0.5
__global__ __launch_bounds__(256) void attn_k(GP gp) {
    const int m = blockIdx.x * 256 + threadIdx.x;
    const int h = blockIdx.y;
    if (m >= NM) return;
    const unsigned char* q = gp.q_sp + (size_t)h * 64 * NM + m;
    int s = 0;
#pragma unroll 8
    for (int d = 0; d < 64; ++d) s += q[(size_t)d * NM];
    float v = gp.t ? gp.v_attn[(size_t)h * NM + m] : 0.0f;
    int sp;
    v = lif_step((float)s, v, 0.5f, sp);
    gp.v_attn[(size_t)h * NM + m] = v;
    gp.attn_sp[(size_t)h * NM + m] = (unsigned char)sp;
}

// x_one = k_sp AND attn_sp (binary product, exact)
__global__ __launch_bounds__(256) void xone_k(GP gp) {
    const int c = blockIdx.y;
    const int m4 = (blockIdx.x * 256 + threadIdx.x) * 4;
    if (m4 >= NM) return;
    const unsigned int kv = *(const unsigned int*)(gp.k_sp + (size_t)c * NM + m4);
    const unsigned int av = *(const unsigned int*)(gp.attn_sp + (size_t)(c >> 6) * NM + m4);
    *(unsigned int*)(gp.x_one + (size_t)c * NM + m4) = kv & av;
}

// ---------------- fused GEMM + BN + LIF ----------------
// R3-proven skeleton: ONE wave per block, wave-private double-buffered LDS,
// ZERO barriers, vmcnt-only sync. Shrunk footprint for occupancy:
// 32o tile, acc<=32, BK=16, LDS 12KB (unfused) / 8KB (fused).
// MODE 0: q&k (O=1024,K=512), X=xT[t], 32o x 64m   unfused mul+add
// MODE 1: proj (O=512,K=512), X=x_one, 32o x 32m   fma (exact)
// MODE 2: mlp1 (O=2048,K=512), X=xy,   32o x 64m   unfused mul+add
// MODE 3: mlp2 (O=512,K=2048), X=h1_sp,32o x 32m   fma; writes out
template <int MODE>
__global__ __launch_bounds__(64) void gemm_lif(GP gp) {
    constexpr bool FUSED = (MODE == 1 || MODE == 3);
    constexpr int K_TOT = (MODE == 3) ? 2048 : 512;
    constexpr int LDA = (MODE == 0) ? 1024 : (MODE == 2) ? 2048 : 512;
    constexpr int BK = 16;
    constexpr int NIT = K_TOT / BK;           // 32 or 128
    constexpr int MT = FUSED ? 32 : 64;       // m-tile
    constexpr int RN = FUSED ? 4 : 8;         // cols per thread

    __shared__ float As[2][BK][32];           // 4 KB
    __shared__ float Xs[2][BK][MT];           // 8 KB (unfused) / 4 KB (fused)

    const int lane = threadIdx.x;
    const int to = lane & 7;                  // o-group: rows to*4..+4
    const int tn = lane >> 3;                 // col-group: cols tn*RN..+RN
    const int m0 = blockIdx.x * MT;
    const int ot = blockIdx.y;                // o-tile (32 channels)
    const int o0 = ot * 32;
    const int mb = m0 + tn * RN;

    const float* wA = (MODE == 0) ? gp.wqkT : (MODE == 1) ? gp.wprojT
                    : (MODE == 2) ? gp.wmlp1T : gp.wmlp2T;
    const float* xf = (MODE == 0) ? gp.xT + (size_t)gp.t * NC * NM : gp.xy;
    const unsigned char* xu = (MODE == 1) ? gp.x_one : gp.h1_sp;

    auto stageA = [&](int buf, int s) {
#pragma unroll
        for (int r = 0; r < 2; ++r)
            gl_lds16(wA + (size_t)(s * BK + r * 8 + (lane >> 3)) * LDA + o0 + (lane & 7) * 4,
                     &As[buf][r * 8][0]);
    };
    auto stageXf = [&](int buf, int s) {
#pragma unroll
        for (int r = 0; r < 4; ++r)
            gl_lds16(xf + (size_t)(s * BK + r * 4 + (lane >> 4)) * NM + m0 + (lane & 15) * 4,
                     &Xs[buf][r * 4][0]);
    };
    // fused byte staging: 16x32 bytes, 8 B/lane
    const int xrow = lane >> 2;               // 0..15
    const int xcb = (lane & 3) * 8;           // 0..24
    auto loadB = [&](int s) -> uint2 {
        return *(const uint2*)(xu + (size_t)(s * BK + xrow) * NM + m0 + xcb);
    };
    auto flushB = [&](int buf, uint2 xb) {
        float* d = &Xs[buf][xrow][xcb];
        float4 f0, f1;
        f0.x = (float)(unsigned char)(xb.x);
        f0.y = (float)(unsigned char)(xb.x >> 8);
        f0.z = (float)(unsigned char)(xb.x >> 16);
        f0.w = (float)(xb.x >> 24);
        f1.x = (float)(unsigned char)(xb.y);
        f1.y = (float)(unsigned char)(xb.y >> 8);
        f1.z = (float)(unsigned char)(xb.y >> 16);
        f1.w = (float)(xb.y >> 24);
        *(float4*)d = f0;
        *(float4*)(d + 4) = f1;
    };

    float acc[4][RN];
#pragma unroll
    for (int i = 0; i < 4; ++i)
#pragma unroll
        for (int j = 0; j < RN; ++j) acc[i][j] = 0.0f;

    auto compute = [&](int cur) {
        if constexpr (!FUSED) {
#pragma unroll 4
            for (int kk = 0; kk < BK; ++kk) {
                const float4 av = *(const float4*)&As[cur][kk][to * 4];
                const float4 x0 = *(const float4*)&Xs[cur][kk][tn * 8];
                const float4 x1 = *(const float4*)&Xs[cur][kk][tn * 8 + 4];
                const float a4[4] = {av.x, av.y, av.z, av.w};
                const float x8[8] = {x0.x, x0.y, x0.z, x0.w, x1.x, x1.y, x1.z, x1.w};
#pragma unroll
                for (int i = 0; i < 4; ++i)
#pragma unroll
                    for (int j = 0; j < 8; ++j)
                        acc[i][j] = __fadd_rn(acc[i][j], __fmul_rn(a4[i], x8[j]));
            }
        } else {
#pragma unroll 8
            for (int kk = 0; kk < BK; ++kk) {
                const float4 av = *(const float4*)&As[cur][kk][to * 4];
                const float4 xv = *(const float4*)&Xs[cur][kk][tn * 4];
                const float a4[4] = {av.x, av.y, av.z, av.w};
                const float x4[4] = {xv.x, xv.y, xv.z, xv.w};
#pragma unroll
                for (int i = 0; i < 4; ++i)
#pragma unroll
                    for (int j = 0; j < 4; ++j)
                        acc[i][j] = __fmaf_rn(a4[i], x4[j], acc[i][j]);
            }
        }
    };

    // ---- prologue ----
    if constexpr (!FUSED) {
        stageA(0, 0); stageXf(0, 0);
        vm0();
    } else {
        stageA(0, 0);
        uint2 xb = loadB(0);
        vm0();
        flushB(0, xb);
        lgkm0();
    }

    // ---- main loop: no barriers (wave-private LDS) ----
#pragma unroll 1
    for (int it = 0; it < NIT; ++it) {
        const int cur = it & 1;
        const int nxt = cur ^ 1;
        const bool more = (it + 1 < NIT);
        if constexpr (!FUSED) {
            if (more) { stageA(nxt, it + 1); stageXf(nxt, it + 1); }
            compute(cur);
            if (more) vm0();
        } else {
            uint2 xb = {0, 0};
            if (more) { stageA(nxt, it + 1); xb = loadB(it + 1); }
            compute(cur);
            if (more) { vm0(); flushB(nxt, xb); lgkm0(); }
        }
    }

    // ---- epilogue: BN + LIF, exact reference op order ----
    if constexpr (MODE == 0) {
        const bool isq = (ot < 16);
        const float* bs = isq ? gp.q_bn_s : gp.k_bn_s;
        const float* bbv = isq ? gp.q_bn_b : gp.k_bn_b;
        float* vb = isq ? gp.v_q : gp.v_k;
        unsigned char* sb = isq ? gp.q_sp : gp.k_sp;
        const int ob = (ot & 15) * 32;
#pragma unroll
        for (int i = 0; i < 4; ++i) {
            const int oo = ob + to * 4 + i;
            const float sc = bs[oo], bc = bbv[oo];
            float* vr = vb + (size_t)oo * NM + mb;
            float vv[8];
            if (gp.t) {
                const float4 v0 = *(const float4*)vr, v1 = *(const float4*)(vr + 4);
                vv[0] = v0.x; vv[1] = v0.y; vv[2] = v0.z; vv[3] = v0.w;
                vv[4] = v1.x; vv[5] = v1.y; vv[6] = v1.z; vv[7] = v1.w;
            } else {
#pragma unroll
                for (int j = 0; j < 8; ++j) vv[j] = 0.0f;
            }
            unsigned int pk[2] = {0, 0};
#pragma unroll
            for (int j = 0; j < 8; ++j) {
                const float z = __fadd_rn(__fmul_rn(acc[i][j], sc), bc);
                int sp;
                vv[j] = lif_step(z, vv[j], 1.0f, sp);
                pk[j >> 2] |= (unsigned)sp << ((j & 3) * 8);
            }
            *(float4*)vr = make_float4(vv[0], vv[1], vv[2], vv[3]);
            *(float4*)(vr + 4) = make_float4(vv[4], vv[5], vv[6], vv[7]);
            *(unsigned int*)(sb + (size_t)oo * NM + mb) = pk[0];
            *(unsigned int*)(sb + (size_t)oo * NM + mb + 4) = pk[1];
        }
    } else if constexpr (MODE == 2) {
        const int ob = ot * 32;
#pragma unroll
        for (int i = 0; i < 4; ++i) {
            const int o = ob + to * 4 + i;
            const float bi = gp.mlp1_b[o], sc = gp.mlp1_bn_s[o], bc = gp.mlp1_bn_b[o];
            float* vr = gp.v_h1 + (size_t)o * NM + mb;
            float vv[8];
            if (gp.t) {
                const float4 v0 = *(const float4*)vr, v1 = *(const float4*)(vr + 4);
                vv[0] = v0.x; vv[1] = v0.y; vv[2] = v0.z; vv[3] = v0.w;
                vv[4] = v1.x; vv[5] = v1.y; vv[6] = v1.z; vv[7] = v1.w;
            } else {
#pragma unroll
                for (int j = 0; j < 8; ++j) vv[j] = 0.0f;
            }
            unsigned int pk[2] = {0, 0};
#pragma unroll
            for (int j = 0; j < 8; ++j) {
                const float z = __fadd_rn(__fmul_rn(__fadd_rn(acc[i][j], bi), sc), bc);
                int sp;
                vv[j] = lif_step(z, vv[j], 1.0f, sp);
                pk[j >> 2] |= (unsigned)sp << ((j & 3) * 8);
            }
            *(float4*)vr = make_float4(vv[0], vv[1], vv[2], vv[3]);
            *(float4*)(vr + 4) = make_float4(vv[4], vv[5], vv[6], vv[7]);
            *(unsigned int*)(gp.h1_sp + (size_t)o * NM + mb) = pk[0];
            *(unsigned int*)(gp.h1_sp + (size_t)o * NM + mb + 4) = pk[1];
        }
    } else if constexpr (MODE == 1) {
        const int ob = ot * 32;
#pragma unroll
        for (int i = 0; i < 4; ++i) {
            const int o = ob + to * 4 + i;
            const float bi = gp.proj_b[o], sc = gp.proj_bn_s[o], bc = gp.proj_bn_b[o];
            float* vr = gp.v_y + (size_t)o * NM + mb;
            const float4 vld = gp.t ? *(const float4*)vr : make_float4(0, 0, 0, 0);
            const float4 xv4 = *(const float4*)(gp.xT + ((size_t)gp.t * NC + o) * NM + mb);
            float vv[4] = {vld.x, vld.y, vld.z, vld.w};
            const float xvv[4] = {xv4.x, xv4.y, xv4.z, xv4.w};
            float xyo[4];
#pragma unroll
            for (int j = 0; j < 4; ++j) {
                const float z = __fadd_rn(__fmul_rn(__fadd_rn(acc[i][j], bi), sc), bc);
                int sp;
                vv[j] = lif_step(z, vv[j], 1.0f, sp);
                xyo[j] = __fadd_rn(xvv[j], (float)sp);   // residual x + y
            }
            *(float4*)vr = make_float4(vv[0], vv[1], vv[2], vv[3]);
            *(float4*)(gp.xy + (size_t)o * NM + mb) = make_float4(xyo[0], xyo[1], xyo[2], xyo[3]);
        }
    } else {  // MODE 3
        const int ob = ot * 32;
        const int b = mb / NN;                // mb%4==0, NN%4==0 -> same b for 4 cols
        const int n = mb - b * NN;
#pragma unroll
        for (int i = 0; i < 4; ++i) {
            const int o = ob + to * 4 + i;
            const float bi = gp.mlp2_b[o], sc = gp.mlp2_bn_s[o], bc = gp.mlp2_bn_b[o];
            float* vr = gp.v_h2 + (size_t)o * NM + mb;
            const float4 vld = gp.t ? *(const float4*)vr : make_float4(0, 0, 0, 0);
            const float4 xyv = *(const float4*)(gp.xy + (size_t)o * NM + mb);
            float vv[4] = {vld.x, vld.y, vld.z, vld.w};
            const float xyf[4] = {xyv.x, xyv.y, xyv.z, xyv.w};
            float ov[4];
#pragma unroll
            for (int j = 0; j < 4; ++j) {
                const float z = __fadd_rn(__fmul_rn(__fadd_rn(acc[i][j], bi), sc), bc);
                int sp;
                vv[j] = lif_step(z, vv[j], 1.0f, sp);
                ov[j] = __fadd_rn(xyf[j], (float)sp);
            }
            *(float4*)&gp.out[(((size_t)gp.t * NB + b) * NC + o) * NN + n] =
                make_float4(ov[0], ov[1], ov[2], ov[3]);
            *(float4*)vr = make_float4(vv[0], vv[1], vv[2], vv[3]);
        }
    }
}

extern "C" void kernel_launch(void* const* d_in, const int* in_sizes, int n_in,
                              void* d_out, int out_size, void* d_ws, size_t ws_size,
                              hipStream_t stream) {
    const float* x       = (const float*)d_in[0];
    const float* q_w     = (const float*)d_in[1];
    const float* k_w     = (const float*)d_in[4];
    const float* proj_w  = (const float*)d_in[7];
    const float* mlp1_w  = (const float*)d_in[11];
    const float* mlp2_w  = (const float*)d_in[15];

    GP gp;
    gp.q_bn_s = (const float*)d_in[2];  gp.q_bn_b = (const float*)d_in[3];
    gp.k_bn_s = (const float*)d_in[5];  gp.k_bn_b = (const float*)d_in[6];
    gp.proj_b = (const float*)d_in[8];  gp.proj_bn_s = (const float*)d_in[9];  gp.proj_bn_b = (const float*)d_in[10];
    gp.mlp1_b = (const float*)d_in[12]; gp.mlp1_bn_s = (const float*)d_in[13]; gp.mlp1_bn_b = (const float*)d_in[14];
    gp.mlp2_b = (const float*)d_in[16]; gp.mlp2_bn_s = (const float*)d_in[17]; gp.mlp2_bn_b = (const float*)d_in[18];
    gp.out = (float*)d_out;

    char* ws = (char*)d_ws;
    size_t off = 0;
    auto alloc = [&](size_t bytes) -> void* {
        void* r = ws + off;
        off += (bytes + 255) & ~(size_t)255;
        return r;
    };
    float* wqkT   = (float*)alloc((size_t)512 * 1024 * 4);
    float* wprojT = (float*)alloc((size_t)512 * 512 * 4);
    float* wmlp1T = (float*)alloc((size_t)512 * 2048 * 4);
    float* wmlp2T = (float*)alloc((size_t)2048 * 512 * 4);
    float* xT     = (float*)alloc((size_t)NT * NC * NM * 4);
    gp.xy     = (float*)alloc((size_t)NC * NM * 4);
    gp.v_q    = (float*)alloc((size_t)NC * NM * 4);
    gp.v_k    = (float*)alloc((size_t)NC * NM * 4);
    gp.v_y    = (float*)alloc((size_t)NC * NM * 4);
    gp.v_h2   = (float*)alloc((size_t)NC * NM * 4);
    gp.v_h1   = (float*)alloc((size_t)NCH * NM * 4);
    gp.v_attn = (float*)alloc((size_t)NH * NM * 4);
    gp.q_sp   = (unsigned char*)alloc((size_t)NC * NM);
    gp.k_sp   = (unsigned char*)alloc((size_t)NC * NM);
    gp.x_one  = (unsigned char*)alloc((size_t)NC * NM);
    gp.h1_sp  = (unsigned char*)alloc((size_t)NCH * NM);
    gp.attn_sp= (unsigned char*)alloc((size_t)NH * NM);
    gp.wqkT = wqkT; gp.wprojT = wprojT; gp.wmlp1T = wmlp1T; gp.wmlp2T = wmlp2T;
    gp.xT = xT;

    // one-time (per call) layout transforms
    trw_k<<<dim3(16, 16), 256, 0, stream>>>(q_w,    wqkT,   512,  1024, 0);
    trw_k<<<dim3(16, 16), 256, 0, stream>>>(k_w,    wqkT,   512,  1024, 512);
    trw_k<<<dim3(16, 16), 256, 0, stream>>>(proj_w, wprojT, 512,  512,  0);
    trw_k<<<dim3(16, 64), 256, 0, stream>>>(mlp1_w, wmlp1T, 512,  2048, 0);
    trw_k<<<dim3(64, 16), 256, 0, stream>>>(mlp2_w, wmlp2T, 2048, 512,  0);
    permx_k<<<NT * NC * NB, 64, 0, stream>>>(x, xT);

    for (int t = 0; t < NT; ++t) {
        gp.t = t;
        gemm_lif<0><<<dim3(98, 32), 64, 0, stream>>>(gp);   // q,k
        attn_k<<<dim3(25, NH), 256, 0, stream>>>(gp);       // attn LIF
        xone_k<<<dim3(7, NC), 256, 0, stream>>>(gp);        // k_sp & attn_sp
        gemm_lif<1><<<dim3(196, 16), 64, 0, stream>>>(gp);  // proj -> v_y, xy
        gemm_lif<2><<<dim3(98, 64), 64, 0, stream>>>(gp);   // mlp1 -> h1_sp
        gemm_lif<3><<<dim3(196, 16), 64, 0, stream>>>(gp);  // mlp2 -> out
    }
}

// Round 9
// 2516.636 us; speedup vs baseline: 4.9877x; 1.0277x over previous
//
#include <hip/hip_runtime.h>
#include <cstdint>

// ---- problem constants ----
#define NT  4
#define NB  32
#define NC  512
#define NCH 2048
#define NN  196
#define NM  (NB * NN)   // 6272 columns = 98*64
#define NH  8

struct GP {
    const float *q_bn_s, *q_bn_b, *k_bn_s, *k_bn_b;
    const float *proj_b, *proj_bn_s, *proj_bn_b;
    const float *mlp1_b, *mlp1_bn_s, *mlp1_bn_b;
    const float *mlp2_b, *mlp2_bn_s, *mlp2_bn_b;
    const float *wqkT, *wprojT, *wmlp1T, *wmlp2T;  // [K][O] transposed weights
    const float *xT;                                // [T][C][M] permuted input
    float *xy;                                      // [C][M] x + y_spike (per t)
    float *v_q, *v_k, *v_y, *v_h1, *v_h2, *v_attn;  // LIF states, [C][M]
    unsigned char *q_sp, *k_sp, *x_one, *h1_sp, *attn_sp; // binary spikes
    float *out;
    int t;
};

// Exact-f32 LIF step (bitwise-validated vs reference in R2-R8).
__device__ __forceinline__ float lif_step(float z, float v_old, float vth, int& sp) {
    float d = __fsub_rn(z, v_old);
    float h = __fmul_rn(d, 0.5f);
    float v = __fadd_rn(v_old, h);
    sp = (v >= vth) ? 1 : 0;
    return sp ? 0.0f : v;
}

typedef const void __attribute__((address_space(1))) gas_t;
typedef void __attribute__((address_space(3))) las_t;
__device__ __forceinline__ void gl_lds16(const float* g, float* l) {
    __builtin_amdgcn_global_load_lds((gas_t*)g, (las_t*)l, 16, 0, 0);
}
__device__ __forceinline__ void vm0() {
    asm volatile("s_waitcnt vmcnt(0)" ::: "memory");
}
__device__ __forceinline__ void vm3() {
    asm volatile("s_waitcnt vmcnt(3)" ::: "memory");
}
__device__ __forceinline__ void lgkm0() {
    asm volatile("s_waitcnt lgkmcnt(0)" ::: "memory");
}

// ---------------- pre-kernels ----------------

// dst[c*ldD + offD + o] = src[o*K + c]   (32x32 LDS tiles)
__global__ __launch_bounds__(256) void trw_k(const float* __restrict__ src,
                                             float* __restrict__ dst,
                                             int K, int ldD, int offD) {
    __shared__ float tle[32][33];
    const int c0 = blockIdx.x * 32, o0 = blockIdx.y * 32;
    const int tx = threadIdx.x & 31, ty = threadIdx.x >> 5;
#pragma unroll
    for (int r = 0; r < 4; ++r)
        tle[ty + r * 8][tx] = src[(size_t)(o0 + ty + r * 8) * K + c0 + tx];
    __syncthreads();
#pragma unroll
    for (int r = 0; r < 4; ++r)
        dst[(size_t)(c0 + ty + r * 8) * ldD + offD + o0 + tx] = tle[tx][ty + r * 8];
}

// xT[t][c][b][n] = x[t][b][c][n]
__global__ __launch_bounds__(64) void permx_k(const float* __restrict__ x,
                                              float* __restrict__ xT) {
    const int id = blockIdx.x;         // t*16384 + c*32 + b
    const int b = id & 31;
    const int c = (id >> 5) & 511;
    const int t = id >> 14;
    const float* s = x + ((size_t)(t * NB + b) * NC + c) * NN;
    float* d = xT + ((size_t)(t * NC + c) * NB + b) * NN;
    for (int n = threadIdx.x; n < NN; n += 64) d[n] = s[n];
}

// attn LIF: per (h,m): integer sum of 64 q-spike bytes; LIF vth=0.5
__global__ __launch_bounds__(256) void attn_k(GP gp) {
    const int m = blockIdx.x * 256 + threadIdx.x;
    const int h = blockIdx.y;
    if (m >= NM) return;
    const unsigned char* q = gp.q_sp + (size_t)h * 64 * NM + m;
    int s = 0;
#pragma unroll 8
    for (int d = 0; d < 64; ++d) s += q[(size_t)d * NM];
    float v = gp.t ? gp.v_attn[(size_t)h * NM + m] : 0.0f;
    int sp;
    v = lif_step((float)s, v, 0.5f, sp);
    gp.v_attn[(size_t)h * NM + m] = v;
    gp.attn_sp[(size_t)h * NM + m] = (unsigned char)sp;
}

// x_one = k_sp AND attn_sp (binary product, exact)
__global__ __launch_bounds__(256) void xone_k(GP gp) {
    const int c = blockIdx.y;
    const int m4 = (blockIdx.x * 256 + threadIdx.x) * 4;
    if (m4 >= NM) return;
    const unsigned int kv = *(const unsigned int*)(gp.k_sp + (size_t)c * NM + m4);
    const unsigned int av = *(const unsigned int*)(gp.attn_sp + (size_t)(c >> 6) * NM + m4);
    *(unsigned int*)(gp.x_one + (size_t)c * NM + m4) = kv & av;
}

// ---------------- fused GEMM + BN + LIF ----------------
// ONE wave per block, wave-private LDS, ZERO barriers, vmcnt-only sync.
// Unfused (MODE 0/2): 2-buffer stage-ahead-1 (compute 2048cyc covers latency).
// Fused (MODE 1/3): 4-buffer ring, stage-ahead-2, counted vmcnt(3) --
//   compute is only 512cyc/iter so 1-deep couldn't hide ~900cyc HBM latency
//   (R8: 46% VALUBusy); Xs rows padded to 36 floats to kill the 16-way
//   ds_write bank conflict (R8: 6.4e6 conflict cycles).
// MODE 0: q&k (O=1024,K=512), X=xT[t], 32o x 64m   unfused mul+add
// MODE 1: proj (O=512,K=512), X=x_one, 32o x 32m   fma (exact)
// MODE 2: mlp1 (O=2048,K=512), X=xy,   32o x 64m   unfused mul+add
// MODE 3: mlp2 (O=512,K=2048), X=h1_sp,32o x 32m   fma; writes out
template <int MODE>
__global__ __launch_bounds__(64) void gemm_lif(GP gp) {
    constexpr bool FUSED = (MODE == 1 || MODE == 3);
    constexpr int K_TOT = (MODE == 3) ? 2048 : 512;
    constexpr int LDA = (MODE == 0) ? 1024 : (MODE == 2) ? 2048 : 512;
    constexpr int BK = 16;
    constexpr int NIT = K_TOT / BK;           // 32 or 128 (divisible by 4)
    constexpr int MT = FUSED ? 32 : 64;       // m-tile
    constexpr int RN = FUSED ? 4 : 8;         // cols per thread
    constexpr int NBUF = FUSED ? 4 : 2;
    constexpr int XP = FUSED ? 36 : MT;       // fused: pad to 144B rows

    __shared__ float As[NBUF][BK][32];
    __shared__ float Xs[NBUF][BK][XP];

    const int lane = threadIdx.x;
    const int to = lane & 7;                  // o-group: rows to*4..+4
    const int tn = lane >> 3;                 // col-group: cols tn*RN..+RN
    const int m0 = blockIdx.x * MT;
    const int ot = blockIdx.y;                // o-tile (32 channels)
    const int o0 = ot * 32;
    const int mb = m0 + tn * RN;

    const float* wA = (MODE == 0) ? gp.wqkT : (MODE == 1) ? gp.wprojT
                    : (MODE == 2) ? gp.wmlp1T : gp.wmlp2T;
    const float* xf = (MODE == 0) ? gp.xT + (size_t)gp.t * NC * NM : gp.xy;
    const unsigned char* xu = (MODE == 1) ? gp.x_one : gp.h1_sp;

    auto stageA = [&](int buf, int s) {
#pragma unroll
        for (int r = 0; r < 2; ++r)
            gl_lds16(wA + (size_t)(s * BK + r * 8 + (lane >> 3)) * LDA + o0 + (lane & 7) * 4,
                     &As[buf][r * 8][0]);
    };
    auto stageXf = [&](int buf, int s) {
#pragma unroll
        for (int r = 0; r < 4; ++r)
            gl_lds16(xf + (size_t)(s * BK + r * 4 + (lane >> 4)) * NM + m0 + (lane & 15) * 4,
                     &Xs[buf][r * 4][0]);
    };
    // fused byte staging: 16x32 bytes, 8 B/lane (1 vmcnt op)
    const int xrow = lane >> 2;               // 0..15
    const int xcb = (lane & 3) * 8;           // 0..24
    auto loadB = [&](int s) -> uint2 {
        return *(const uint2*)(xu + (size_t)(s * BK + xrow) * NM + m0 + xcb);
    };
    auto flushB = [&](int buf, uint2 xb) {
        float* d = &Xs[buf][xrow][xcb];       // padded row: 2-way banks only
        float4 f0, f1;
        f0.x = (float)(unsigned char)(xb.x);
        f0.y = (float)(unsigned char)(xb.x >> 8);
        f0.z = (float)(unsigned char)(xb.x >> 16);
        f0.w = (float)(xb.x >> 24);
        f1.x = (float)(unsigned char)(xb.y);
        f1.y = (float)(unsigned char)(xb.y >> 8);
        f1.z = (float)(unsigned char)(xb.y >> 16);
        f1.w = (float)(xb.y >> 24);
        *(float4*)d = f0;
        *(float4*)(d + 4) = f1;
    };

    float acc[4][RN];
#pragma unroll
    for (int i = 0; i < 4; ++i)
#pragma unroll
        for (int j = 0; j < RN; ++j) acc[i][j] = 0.0f;

    auto compute = [&](int cur) {
        if constexpr (!FUSED) {
#pragma unroll 4
            for (int kk = 0; kk < BK; ++kk) {
                const float4 av = *(const float4*)&As[cur][kk][to * 4];
                const float4 x0 = *(const float4*)&Xs[cur][kk][tn * 8];
                const float4 x1 = *(const float4*)&Xs[cur][kk][tn * 8 + 4];
                const float a4[4] = {av.x, av.y, av.z, av.w};
                const float x8[8] = {x0.x, x0.y, x0.z, x0.w, x1.x, x1.y, x1.z, x1.w};
#pragma unroll
                for (int i = 0; i < 4; ++i)
#pragma unroll
                    for (int j = 0; j < 8; ++j)
                        acc[i][j] = __fadd_rn(acc[i][j], __fmul_rn(a4[i], x8[j]));
            }
        } else {
#pragma unroll 8
            for (int kk = 0; kk < BK; ++kk) {
                const float4 av = *(const float4*)&As[cur][kk][to * 4];
                const float4 xv = *(const float4*)&Xs[cur][kk][tn * 4];
                const float a4[4] = {av.x, av.y, av.z, av.w};
                const float x4[4] = {xv.x, xv.y, xv.z, xv.w};
#pragma unroll
                for (int i = 0; i < 4; ++i)
#pragma unroll
                    for (int j = 0; j < 4; ++j)
                        acc[i][j] = __fmaf_rn(a4[i], x4[j], acc[i][j]);
            }
        }
    };

    if constexpr (!FUSED) {
        // ---- unfused: 2-buffer, stage-ahead 1 (proven in R8) ----
        stageA(0, 0); stageXf(0, 0);
        vm0();
#pragma unroll 1
        for (int it = 0; it < NIT; ++it) {
            const int cur = it & 1;
            const bool more = (it + 1 < NIT);
            if (more) { stageA(cur ^ 1, it + 1); stageXf(cur ^ 1, it + 1); }
            compute(cur);
            if (more) vm0();
        }
    } else {
        // ---- fused: 4-buffer ring, stage-ahead 2, counted vmcnt ----
        uint2 sl0, sl1;                       // byte-slot ping-pong
        stageA(0, 0); sl0 = loadB(0);
        stageA(1, 1); sl1 = loadB(1);
        vm3();                                // stage0 retired (stage1 in flight)
        flushB(0, sl0);
        lgkm0();

        auto body = [&](int i, int cb, uint2& sStage, uint2& sFlush) {
            if (i + 2 < NIT) { stageA((cb + 2) & 3, i + 2); sStage = loadB(i + 2); }
            compute(cb);
            if (i + 1 < NIT) {
                if (NIT - 1 - i >= 2) vm3(); else vm0();
                flushB((cb + 1) & 3, sFlush);
                lgkm0();
            }
        };
#pragma unroll 1
        for (int i = 0; i < NIT; i += 4) {
            body(i + 0, 0, sl0, sl1);
            body(i + 1, 1, sl1, sl0);
            body(i + 2, 2, sl0, sl1);
            body(i + 3, 3, sl1, sl0);
        }
    }

    // ---- epilogue: BN + LIF, exact reference op order ----
    if constexpr (MODE == 0) {
        const bool isq = (ot < 16);
        const float* bs = isq ? gp.q_bn_s : gp.k_bn_s;
        const float* bbv = isq ? gp.q_bn_b : gp.k_bn_b;
        float* vb = isq ? gp.v_q : gp.v_k;
        unsigned char* sb = isq ? gp.q_sp : gp.k_sp;
        const int ob = (ot & 15) * 32;
#pragma unroll
        for (int i = 0; i < 4; ++i) {
            const int oo = ob + to * 4 + i;
            const float sc = bs[oo], bc = bbv[oo];
            float* vr = vb + (size_t)oo * NM + mb;
            float vv[8];
            if (gp.t) {
                const float4 v0 = *(const float4*)vr, v1 = *(const float4*)(vr + 4);
                vv[0] = v0.x; vv[1] = v0.y; vv[2] = v0.z; vv[3] = v0.w;
                vv[4] = v1.x; vv[5] = v1.y; vv[6] = v1.z; vv[7] = v1.w;
            } else {
#pragma unroll
                for (int j = 0; j < 8; ++j) vv[j] = 0.0f;
            }
            unsigned int pk[2] = {0, 0};
#pragma unroll
            for (int j = 0; j < 8; ++j) {
                const float z = __fadd_rn(__fmul_rn(acc[i][j], sc), bc);
                int sp;
                vv[j] = lif_step(z, vv[j], 1.0f, sp);
                pk[j >> 2] |= (unsigned)sp << ((j & 3) * 8);
            }
            *(float4*)vr = make_float4(vv[0], vv[1], vv[2], vv[3]);
            *(float4*)(vr + 4) = make_float4(vv[4], vv[5], vv[6], vv[7]);
            *(unsigned int*)(sb + (size_t)oo * NM + mb) = pk[0];
            *(unsigned int*)(sb + (size_t)oo * NM + mb + 4) = pk[1];
        }
    } else if constexpr (MODE == 2) {
        const int ob = ot * 32;
#pragma unroll
        for (int i = 0; i < 4; ++i) {
            const int o = ob + to * 4 + i;
            const float bi = gp.mlp1_b[o], sc = gp.mlp1_bn_s[o], bc = gp.mlp1_bn_b[o];
            float* vr = gp.v_h1 + (size_t)o * NM + mb;
            float vv[8];
            if (gp.t) {
                const float4 v0 = *(const float4*)vr, v1 = *(const float4*)(vr + 4);
                vv[0] = v0.x; vv[1] = v0.y; vv[2] = v0.z; vv[3] = v0.w;
                vv[4] = v1.x; vv[5] = v1.y; vv[6] = v1.z; vv[7] = v1.w;
            } else {
#pragma unroll
                for (int j = 0; j < 8; ++j) vv[j] = 0.0f;
            }
            unsigned int pk[2] = {0, 0};
#pragma unroll
            for (int j = 0; j < 8; ++j) {
                const float z = __fadd_rn(__fmul_rn(__fadd_rn(acc[i][j], bi), sc), bc);
                int sp;
                vv[j] = lif_step(z, vv[j], 1.0f, sp);
                pk[j >> 2] |= (unsigned)sp << ((j & 3) * 8);
            }
            *(float4*)vr = make_float4(vv[0], vv[1], vv[2], vv[3]);
            *(float4*)(vr + 4) = make_float4(vv[4], vv[5], vv[6], vv[7]);
            *(unsigned int*)(gp.h1_sp + (size_t)o * NM + mb) = pk[0];
            *(unsigned int*)(gp.h1_sp + (size_t)o * NM + mb + 4) = pk[1];
        }
    } else if constexpr (MODE == 1) {
        const int ob = ot * 32;
#pragma unroll
        for (int i = 0; i < 4; ++i) {
            const int o = ob + to * 4 + i;
            const float bi = gp.proj_b[o], sc = gp.proj_bn_s[o], bc = gp.proj_bn_b[o];
            float* vr = gp.v_y + (size_t)o * NM + mb;
            const float4 vld = gp.t ? *(const float4*)vr : make_float4(0, 0, 0, 0);
            const float4 xv4 = *(const float4*)(gp.xT + ((size_t)gp.t * NC + o) * NM + mb);
            float vv[4] = {vld.x, vld.y, vld.z, vld.w};
            const float xvv[4] = {xv4.x, xv4.y, xv4.z, xv4.w};
            float xyo[4];
#pragma unroll
            for (int j = 0; j < 4; ++j) {
                const float z = __fadd_rn(__fmul_rn(__fadd_rn(acc[i][j], bi), sc), bc);
                int sp;
                vv[j] = lif_step(z, vv[j], 1.0f, sp);
                xyo[j] = __fadd_rn(xvv[j], (float)sp);   // residual x + y
            }
            *(float4*)vr = make_float4(vv[0], vv[1], vv[2], vv[3]);
            *(float4*)(gp.xy + (size_t)o * NM + mb) = make_float4(xyo[0], xyo[1], xyo[2], xyo[3]);
        }
    } else {  // MODE 3
        const int ob = ot * 32;
        const int b = mb / NN;                // mb%4==0, NN%4==0 -> same b for 4 cols
        const int n = mb - b * NN;
#pragma unroll
        for (int i = 0; i < 4; ++i) {
            const int o = ob + to * 4 + i;
            const float bi = gp.mlp2_b[o], sc = gp.mlp2_bn_s[o], bc = gp.mlp2_bn_b[o];
            float* vr = gp.v_h2 + (size_t)o * NM + mb;
            const float4 vld = gp.t ? *(const float4*)vr : make_float4(0, 0, 0, 0);
            const float4 xyv = *(const float4*)(gp.xy + (size_t)o * NM + mb);
            float vv[4] = {vld.x, vld.y, vld.z, vld.w};
            const float xyf[4] = {xyv.x, xyv.y, xyv.z, xyv.w};
            float ov[4];
#pragma unroll
            for (int j = 0; j < 4; ++j) {
                const float z = __fadd_rn(__fmul_rn(__fadd_rn(acc[i][j], bi), sc), bc);
                int sp;
                vv[j] = lif_step(z, vv[j], 1.0f, sp);
                ov[j] = __fadd_rn(xyf[j], (float)sp);
            }
            *(float4*)&gp.out[(((size_t)gp.t * NB + b) * NC + o) * NN + n] =
                make_float4(ov[0], ov[1], ov[2], ov[3]);
            *(float4*)vr = make_float4(vv[0], vv[1], vv[2], vv[3]);
        }
    }
}

extern "C" void kernel_launch(void* const* d_in, const int* in_sizes, int n_in,
                              void* d_out, int out_size, void* d_ws, size_t ws_size,
                              hipStream_t stream) {
    const float* x       = (const float*)d_in[0];
    const float* q_w     = (const float*)d_in[1];
    const float* k_w     = (const float*)d_in[4];
    const float* proj_w  = (const float*)d_in[7];
    const float* mlp1_w  = (const float*)d_in[11];
    const float* mlp2_w  = (const float*)d_in[15];

    GP gp;
    gp.q_bn_s = (const float*)d_in[2];  gp.q_bn_b = (const float*)d_in[3];
    gp.k_bn_s = (const float*)d_in[5];  gp.k_bn_b = (const float*)d_in[6];
    gp.proj_b = (const float*)d_in[8];  gp.proj_bn_s = (const float*)d_in[9];  gp.proj_bn_b = (const float*)d_in[10];
    gp.mlp1_b = (const float*)d_in[12]; gp.mlp1_bn_s = (const float*)d_in[13]; gp.mlp1_bn_b = (const float*)d_in[14];
    gp.mlp2_b = (const float*)d_in[16]; gp.mlp2_bn_s = (const float*)d_in[17]; gp.mlp2_bn_b = (const float*)d_in[18];
    gp.out = (float*)d_out;

    char* ws = (char*)d_ws;
    size_t off = 0;
    auto alloc = [&](size_t bytes) -> void* {
        void* r = ws + off;
        off += (bytes + 255) & ~(size_t)255;
        return r;
    };
    float* wqkT   = (float*)alloc((size_t)512 * 1024 * 4);
    float* wprojT = (float*)alloc((size_t)512 * 512 * 4);
    float* wmlp1T = (float*)alloc((size_t)512 * 2048 * 4);
    float* wmlp2T = (float*)alloc((size_t)2048 * 512 * 4);
    float* xT     = (float*)alloc((size_t)NT * NC * NM * 4);
    gp.xy     = (float*)alloc((size_t)NC * NM * 4);
    gp.v_q    = (float*)alloc((size_t)NC * NM * 4);
    gp.v_k    = (float*)alloc((size_t)NC * NM * 4);
    gp.v_y    = (float*)alloc((size_t)NC * NM * 4);
    gp.v_h2   = (float*)alloc((size_t)NC * NM * 4);
    gp.v_h1   = (float*)alloc((size_t)NCH * NM * 4);
    gp.v_attn = (float*)alloc((size_t)NH * NM * 4);
    gp.q_sp   = (unsigned char*)alloc((size_t)NC * NM);
    gp.k_sp   = (unsigned char*)alloc((size_t)NC * NM);
    gp.x_one  = (unsigned char*)alloc((size_t)NC * NM);
    gp.h1_sp  = (unsigned char*)alloc((size_t)NCH * NM);
    gp.attn_sp= (unsigned char*)alloc((size_t)NH * NM);
    gp.wqkT = wqkT; gp.wprojT = wprojT; gp.wmlp1T = wmlp1T; gp.wmlp2T = wmlp2T;
    gp.xT = xT;

    // one-time (per call) layout transforms
    trw_k<<<dim3(16, 16), 256, 0, stream>>>(q_w,    wqkT,   512,  1024, 0);
    trw_k<<<dim3(16, 16), 256, 0, stream>>>(k_w,    wqkT,   512,  1024, 512);
    trw_k<<<dim3(16, 16), 256, 0, stream>>>(proj_w, wprojT, 512,  512,  0);
    trw_k<<<dim3(16, 64), 256, 0, stream>>>(mlp1_w, wmlp1T, 512,  2048, 0);
    trw_k<<<dim3(64, 16), 256, 0, stream>>>(mlp2_w, wmlp2T, 2048, 512,  0);
    permx_k<<<NT * NC * NB, 64, 0, stream>>>(x, xT);

    for (int t = 0; t < NT; ++t) {
        gp.t = t;
        gemm_lif<0><<<dim3(98, 32), 64, 0, stream>>>(gp);   // q,k
        attn_k<<<dim3(25, NH), 256, 0, stream>>>(gp);       // attn LIF
        xone_k<<<dim3(7, NC), 256, 0, stream>>>(gp);        // k_sp & attn_sp
        gemm_lif<1><<<dim3(196, 16), 64, 0, stream>>>(gp);  // proj -> v_y, xy
        gemm_lif<2><<<dim3(98, 64), 64, 0, stream>>>(gp);   // mlp1 -> h1_sp
        gemm_lif<3><<<dim3(196, 16), 64, 0, stream>>>(gp);  // mlp2 -> out
    }
}